// Round 1
// 339.622 us; speedup vs baseline: 1.1216x; 1.1216x over previous
//
#include <hip/hip_runtime.h>
#include <math.h>

#define BATCH 16
#define P 32768
#define C 81
#define CM1 80
#define NCAND 400
#define NOUT 100
#define NBINS 256
#define SMIN_F (-3.0f)
#define BIN_SCALE (NBINS / 3.0f)
#define SORTN 1024
#define ROWCAP 1024
#define IMG_SZ 512.0f
#define NMS_THR 0.45f
#define NWORDS 7
#define NPAD 448
#define RPB 64  // rows per block in the streaming pass

// ---- workspace layout (bytes) ----
#define OFF_HIST 0                              // BATCH*NBINS*4 = 16384
#define OFF_MAXSC 16384                         // BATCH*P*4 = 2 MB (16B-aligned)
#define NEED_WS (OFF_MAXSC + (size_t)BATCH * P * 4)

__device__ __forceinline__ int score_bin(float sc) {
    int b = (int)((sc - SMIN_F) * BIN_SCALE);
    return b < 0 ? 0 : (b > NBINS - 1 ? NBINS - 1 : b);
}

// Quad-per-row stats. MUST be bit-identical between k_hist (LDS source) and
// k_post (global source): lane q of a 4-lane quad holds columns c = 4k+q,
// reductions via xor-1/xor-2. Same float values + same op order -> same bits.
__device__ __forceinline__ void quad_stats(const float* __restrict__ rowp, int q,
                                           float r[21], float& m, float& l, float& fg) {
#pragma unroll
    for (int k = 0; k < 21; ++k) {
        int c = 4 * k + q;
        r[k] = (c < C) ? rowp[c] : -INFINITY;
    }
    float mm = -INFINITY;
#pragma unroll
    for (int k = 0; k < 21; ++k) mm = fmaxf(mm, r[k]);
    mm = fmaxf(mm, __shfl_xor(mm, 1));
    mm = fmaxf(mm, __shfl_xor(mm, 2));
    float s = 0.0f;
#pragma unroll
    for (int k = 0; k < 21; ++k) {
        int c = 4 * k + q;
        if (c < C) s += __expf(r[k] - mm);
    }
    s += __shfl_xor(s, 1);
    s += __shfl_xor(s, 2);
    float fgm = -INFINITY;
#pragma unroll
    for (int k = 0; k < 21; ++k) {
        int c = 4 * k + q;
        if (c >= 1 && c < C) fgm = fmaxf(fgm, r[k]);
    }
    fgm = fmaxf(fgm, __shfl_xor(fgm, 1));
    fgm = fmaxf(fgm, __shfl_xor(fgm, 2));
    m = mm;
    l = __logf(s);
    fg = fgm;
}

__device__ __forceinline__ unsigned long long pack_key(float v, unsigned id) {
    unsigned bits = __float_as_uint(v);
    unsigned u = (bits & 0x80000000u) ? ~bits : (bits | 0x80000000u);
    return ((unsigned long long)(~u) << 32) | id;  // asc key == desc value, asc idx
}

// ---- pass 1: linear float4 staging into LDS, quad-per-row stats,
// histogram of scores > SMIN_F + per-row max score.
__global__ __launch_bounds__(256) void k_hist(const float* __restrict__ logits,
                                              unsigned* __restrict__ hist,
                                              float* __restrict__ maxsc) {
    __shared__ float tile[RPB * C];  // 20736 B
    __shared__ unsigned lh[NBINS];   // 1 KB
    int img = blockIdx.y;
    int row0 = blockIdx.x * RPB;
    lh[threadIdx.x] = 0;
    const float4* g4 = (const float4*)(logits + ((size_t)img * P + row0) * C);
    float4* t4 = (float4*)tile;
#pragma unroll
    for (int i = 0; i < 6; ++i) {
        int idx = threadIdx.x + i * 256;
        if (idx < RPB * C / 4) t4[idx] = g4[idx];
    }
    __syncthreads();
    int quad = threadIdx.x >> 2, q = threadIdx.x & 3;
    const float* rowp = tile + quad * C;
    float r[21], m, l, fg;
    quad_stats(rowp, q, r, m, l, fg);
    if (q == 0) maxsc[(size_t)img * P + row0 + quad] = (fg - m) - l;
#pragma unroll
    for (int k = 0; k < 21; ++k) {
        int c = 4 * k + q;
        if (c >= 1 && c < C) {
            float sc = (r[k] - m) - l;
            if (sc > SMIN_F) atomicAdd(&lh[score_bin(sc)], 1u);
        }
    }
    __syncthreads();
    unsigned h = lh[threadIdx.x];
    if (h) atomicAdd(&hist[(size_t)img * NBINS + threadIdx.x], h);
}

// ---- pass 2: one block per image, 1024 threads (16 waves).
// threshold -> row compact -> recompute -> register bitonic sort -> decode ->
// IoU -> greedy NMS -> outputs.
__global__ __launch_bounds__(1024) void k_post(const float* __restrict__ logits,
                                               const float* __restrict__ bbox,
                                               const float* __restrict__ priors,
                                               const unsigned* __restrict__ hist,
                                               const float* __restrict__ maxsc,
                                               float* __restrict__ out) {
    __shared__ int tb_sh, nrows_sh, ncand_sh;
    __shared__ int rowlist[ROWCAP];
    __shared__ unsigned long long key[SORTN];
    __shared__ float x1[NCAND], y1[NCAND], x2[NCAND], y2[NCAND];
    __shared__ float ox1[NPAD], oy1[NPAD], ox2[NPAD], oy2[NPAD], areas[NPAD];
    __shared__ float scs[NCAND];
    __shared__ int lab[NCAND];
    __shared__ unsigned long long M[NPAD][NWORDS];
    __shared__ unsigned long long keepw_s[NWORDS];
    __shared__ int wpre_s[NWORDS + 1];
    __shared__ float wred[16];
    __shared__ float maxc_sh;
    __shared__ int kidx[NOUT];

    int img = blockIdx.x;
    int tid = threadIdx.x;
    int lane = tid & 63;
    int wv = tid >> 6;

    if (tid == 0) { tb_sh = 0; nrows_sh = 0; ncand_sh = 0; }

    // prefetch this image's row-max scores into registers; the 128 KB read
    // latency hides under the histogram scan below.
    float4 msv[P / 4 / 1024];
    const float4* ms4 = (const float4*)(maxsc + (size_t)img * P);
#pragma unroll
    for (int i = 0; i < P / 4 / 1024; ++i) msv[i] = ms4[tid + i * 1024];

    key[tid] = pack_key(-INFINITY, 0x7FFFFFFFu);

    // wave 0: histogram suffix-scan -> threshold bin. Exact unsigned sums,
    // identical tb to the old LDS tree scan.
    if (wv == 0) {
        uint4 h4 = ((const uint4*)(hist + (size_t)img * NBINS))[lane];
        unsigned own = h4.x + h4.y + h4.z + h4.w;
        unsigned acc = own;
#pragma unroll
        for (int off = 1; off < 64; off <<= 1) {
            unsigned t = __shfl_down(acc, off);
            if (lane + off < 64) acc += t;
        }
        unsigned above = acc - own;        // sum of bins >= 4*(lane+1)
        unsigned s3 = above + h4.w;        // suffix(4*lane+3)
        unsigned s2 = s3 + h4.z;
        unsigned s1 = s2 + h4.y;
        unsigned s0 = s1 + h4.x;           // suffix(4*lane)
        int best = -1;
        if (s0 >= NCAND) best = 4 * lane + 0;
        if (s1 >= NCAND) best = 4 * lane + 1;
        if (s2 >= NCAND) best = 4 * lane + 2;
        if (s3 >= NCAND) best = 4 * lane + 3;
#pragma unroll
        for (int off = 32; off >= 1; off >>= 1) {
            int o = __shfl_xor(best, off);
            best = best > o ? best : o;
        }
        if (lane == 0) tb_sh = best < 0 ? 0 : best;
    }
    __syncthreads();
    int tb = tb_sh;

    // compact qualifying rows (maxsc monotone-exact vs per-candidate filter)
#pragma unroll
    for (int i = 0; i < P / 4 / 1024; ++i) {
        float4 v4 = msv[i];
        int rbase = (tid + i * 1024) * 4;
        float vv[4] = {v4.x, v4.y, v4.z, v4.w};
#pragma unroll
        for (int j = 0; j < 4; ++j) {
            if (vv[j] > SMIN_F && score_bin(vv[j]) >= tb) {
                int pos = atomicAdd(&nrows_sh, 1);
                if (pos < ROWCAP) rowlist[pos] = rbase + j;
            }
        }
    }
    __syncthreads();
    int nrows = nrows_sh;
    if (nrows > ROWCAP) nrows = ROWCAP;

    // recompute scores for qualifying rows only; scatter sort keys
    {
        int quad = tid >> 2, q = tid & 3;  // 256 quads
        for (int base = 0; base < nrows; base += 256) {
            int ri = base + quad;
            if (ri < nrows) {
                int row = rowlist[ri];
                const float* rowp = logits + ((size_t)img * P + row) * C;
                float r[21], m, l, fg;
                quad_stats(rowp, q, r, m, l, fg);
#pragma unroll
                for (int k = 0; k < 21; ++k) {
                    int c = 4 * k + q;
                    if (c >= 1 && c < C) {
                        float sc = (r[k] - m) - l;
                        if (sc > SMIN_F && score_bin(sc) >= tb) {
                            int pos = atomicAdd(&ncand_sh, 1);
                            if (pos < SORTN)
                                key[pos] = pack_key(sc, (unsigned)(row * CM1 + c - 1));
                        }
                    }
                }
            }
        }
    }
    __syncthreads();

    // register-resident bitonic sort, ascending on u64 keys.
    // thread t owns element t. j<=32 phases are intra-wave (shfl_xor, no
    // barrier) - 45 of 55 phases. Only j>=64 phases exchange through LDS.
    // Identical network/compare order to the old LDS sort -> identical result.
    unsigned long long kr = key[tid];
#pragma unroll
    for (int k2 = 2; k2 <= 64; k2 <<= 1) {
        for (int j = k2 >> 1; j > 0; j >>= 1) {
            unsigned long long pv = __shfl_xor(kr, j);
            bool takeMin = (((tid & j) == 0) == ((tid & k2) == 0));
            bool sel = takeMin ? (pv < kr) : (pv > kr);
            if (sel) kr = pv;
        }
    }
    for (int k2 = 128; k2 <= SORTN; k2 <<= 1) {
        for (int j = k2 >> 1; j >= 64; j >>= 1) {
            __syncthreads();   // prior phase's reads done before overwrite
            key[tid] = kr;
            __syncthreads();
            unsigned long long pv = key[tid ^ j];
            bool takeMin = (((tid & j) == 0) == ((tid & k2) == 0));
            bool sel = takeMin ? (pv < kr) : (pv > kr);
            if (sel) kr = pv;
        }
#pragma unroll
        for (int j = 32; j > 0; j >>= 1) {
            unsigned long long pv = __shfl_xor(kr, j);
            bool takeMin = (((tid & j) == 0) == ((tid & k2) == 0));
            bool sel = takeMin ? (pv < kr) : (pv > kr);
            if (sel) kr = pv;
        }
    }

    // decode top-400 (element tid lives in thread tid's register)
    if (tid < NCAND) {
        unsigned uu = ~(unsigned)(kr >> 32);
        unsigned bits = (uu & 0x80000000u) ? (uu & 0x7FFFFFFFu) : ~uu;
        scs[tid] = __uint_as_float(bits);
        unsigned f = (unsigned)(kr & 0xFFFFFFFFu);
        if (f > (unsigned)(P * CM1 - 1)) f = (unsigned)(P * CM1 - 1);
        int p = (int)(f / CM1);
        int c = (int)(f % CM1) + 1;
        const float* lp = bbox + ((size_t)img * P + p) * 4;
        const float* pp = priors + (size_t)p * 4;
        float cx = lp[0] * 0.1f * pp[2] + pp[0];
        float cy = lp[1] * 0.1f * pp[3] + pp[1];
        float w = expf(lp[2] * 0.2f) * pp[2];
        float h = expf(lp[3] * 0.2f) * pp[3];
        x1[tid] = (cx - w * 0.5f) * IMG_SZ;
        y1[tid] = (cy - h * 0.5f) * IMG_SZ;
        x2[tid] = (cx + w * 0.5f) * IMG_SZ;
        y2[tid] = (cy + h * 0.5f) * IMG_SZ;
        lab[tid] = c;
    }
    __syncthreads();

    float mx = -INFINITY;
    if (tid < NCAND) mx = fmaxf(fmaxf(x1[tid], y1[tid]), fmaxf(x2[tid], y2[tid]));
#pragma unroll
    for (int off = 32; off >= 1; off >>= 1) mx = fmaxf(mx, __shfl_xor(mx, off));
    if (lane == 0) wred[wv] = mx;
    __syncthreads();
    if (tid == 0) {
        float mm = -INFINITY;
        for (int t = 0; t < 16; ++t) mm = fmaxf(mm, wred[t]);
        maxc_sh = mm;
    }
    __syncthreads();

    if (tid < NPAD) {
        if (tid < NCAND) {
            float off = (float)lab[tid] * (maxc_sh + 1.0f);
            ox1[tid] = x1[tid] + off;
            oy1[tid] = y1[tid] + off;
            ox2[tid] = x2[tid] + off;
            oy2[tid] = y2[tid] + off;
            areas[tid] = (ox2[tid] - ox1[tid]) * (oy2[tid] - oy1[tid]);
        } else {
            ox1[tid] = 1e30f; oy1[tid] = 1e30f;
            ox2[tid] = 1e30f; oy2[tid] = 1e30f;
            areas[tid] = 0.0f;
        }
    }
    __syncthreads();

    // IoU masks via ballot (16 waves)
    for (int i = wv; i < NCAND; i += 16) {
        float a1 = ox1[i], b1 = oy1[i], a2 = ox2[i], b2 = oy2[i], ar = areas[i];
#pragma unroll
        for (int wd = 0; wd < NWORDS; ++wd) {
            int j = wd * 64 + lane;
            float iw_ = fmaxf(fminf(a2, ox2[j]) - fmaxf(a1, ox1[j]), 0.0f);
            float ih_ = fmaxf(fminf(b2, oy2[j]) - fmaxf(b1, oy1[j]), 0.0f);
            float inter = iw_ * ih_;
            float uni = ar + areas[j] - inter;
            float iou = inter / fmaxf(uni, 1e-12f);
            unsigned long long bits = __ballot(iou > NMS_THR);
            if (lane == 0) M[i][wd] = bits;
        }
    }
    __syncthreads();

    // greedy NMS: wave 0, M rows pre-distributed across lanes, readlane core.
    // Only accumulate suppression into current/future words (past words dead).
    if (wv == 0) {
        unsigned long long acc[NWORDS] = {0, 0, 0, 0, 0, 0, 0};
        unsigned long long keepw[NWORDS];
#pragma unroll
        for (int iw = 0; iw < NWORDS; ++iw) {
            unsigned long long mrow[NWORDS];
#pragma unroll
            for (int w = iw; w < NWORDS; ++w) mrow[w] = M[iw * 64 + lane][w];
            unsigned long long sup = acc[iw];
            unsigned long long K = 0;
            int nb = (iw == NWORDS - 1) ? (NCAND - 64 * (NWORDS - 1)) : 64;
            for (int ib = 0; ib < nb; ++ib) {
                if (!((sup >> ib) & 1ull)) {
                    K |= (1ull << ib);
                    int lo, hi;
                    lo = __builtin_amdgcn_readlane((int)(unsigned)mrow[iw], ib);
                    hi = __builtin_amdgcn_readlane((int)(unsigned)(mrow[iw] >> 32), ib);
                    sup |= ((unsigned long long)(unsigned)hi << 32) | (unsigned)lo;
#pragma unroll
                    for (int w = iw + 1; w < NWORDS; ++w) {
                        lo = __builtin_amdgcn_readlane((int)(unsigned)mrow[w], ib);
                        hi = __builtin_amdgcn_readlane((int)(unsigned)(mrow[w] >> 32), ib);
                        acc[w] |= ((unsigned long long)(unsigned)hi << 32) | (unsigned)lo;
                    }
                }
            }
            keepw[iw] = K;
        }
        if (lane == 0) {
            int a = 0;
#pragma unroll
            for (int w = 0; w < NWORDS; ++w) {
                keepw_s[w] = keepw[w];
                wpre_s[w] = a;
                a += __popcll(keepw[w]);
            }
            wpre_s[NWORDS] = a;
        }
    }
    __syncthreads();

    // kidx: kept (ascending) then unkept (ascending)
    if (tid < NCAND) {
        int w = tid >> 6, bb = tid & 63;
        unsigned long long kwv = keepw_s[w];
        bool kp = (kwv >> bb) & 1ull;
        unsigned long long below_mask = (bb == 0) ? 0ull : (~0ull >> (64 - bb));
        int below = wpre_s[w] + __popcll(kwv & below_mask);
        int nkept = wpre_s[NWORDS];
        int pos = kp ? below : nkept + (tid - below);
        if (pos < NOUT) kidx[pos] = tid;
    }
    __syncthreads();

    if (tid < NOUT) {
        int i = kidx[tid];
        bool kp = (keepw_s[i >> 6] >> (i & 63)) & 1ull;
        float* ob = out + ((size_t)img * NOUT + tid) * 4;
        ob[0] = x1[i];
        ob[1] = y1[i];
        ob[2] = x2[i];
        ob[3] = y2[i];
        out[(size_t)BATCH * NOUT * 4 + (size_t)img * NOUT + tid] = (float)lab[i];
        out[(size_t)BATCH * NOUT * 4 + (size_t)BATCH * NOUT + (size_t)img * NOUT + tid] =
            kp ? scs[i] : -INFINITY;
    }
}

extern "C" void kernel_launch(void* const* d_in, const int* in_sizes, int n_in,
                              void* d_out, int out_size, void* d_ws, size_t ws_size,
                              hipStream_t stream) {
    const float* logits = (const float*)d_in[0];
    const float* bbox = (const float*)d_in[1];
    const float* priors = (const float*)d_in[2];
    float* out = (float*)d_out;
    char* ws = (char*)d_ws;

    unsigned* hist = (unsigned*)(ws + OFF_HIST);
    float* maxsc = (float*)(ws + OFF_MAXSC);

    hipMemsetAsync(ws, 0, OFF_MAXSC, stream);  // zero hist

    dim3 g1(P / RPB, BATCH);
    k_hist<<<g1, 256, 0, stream>>>(logits, hist, maxsc);
    k_post<<<BATCH, 1024, 0, stream>>>(logits, bbox, priors, hist, maxsc, out);
}